// Round 9
// baseline (1812.722 us; speedup 1.0000x reference)
//
#include <hip/hip_runtime.h>
#include <hip/hip_bf16.h>
#include <math.h>

typedef __attribute__((ext_vector_type(4))) float f32x4;
typedef __attribute__((ext_vector_type(8))) short s16x8;
typedef __attribute__((ext_vector_type(4))) unsigned short u16x4;

#define MFMA16(a, b, c) __builtin_amdgcn_mfma_f32_16x16x32_bf16(a, b, c, 0, 0, 0)

static constexpr int BB = 32, TT = 128, EE = 512, HH = 1024, VV = 32000;
static constexpr int FH = 4 * HH;           // 4096 gate rows
static constexpr int MROWS = (TT - 1) * BB; // 4064 valid rows
static constexpr int MPAD = 4096;
static constexpr int BH = BB * HH;          // 32768
static constexpr int NREC = 256;            // recurrence blocks (barrier members)
static constexpr int NWRK = 256;            // projection worker blocks
static constexpr int NTILE = 8000;          // 32 m-tiles x 250 n-tiles

__device__ __forceinline__ unsigned short f2bf(float f) {
  unsigned int u = __float_as_uint(f);
  u = (u + 0x7FFFu + ((u >> 16) & 1u)) >> 16;
  return (unsigned short)u;
}
__device__ __forceinline__ float sigf(float x) { return 1.f / (1.f + __expf(-x)); }

__device__ __forceinline__ s16x8 pack8f(const float* p) {
  float4 x = *(const float4*)p;
  float4 y = *(const float4*)(p + 4);
  s16x8 r;
  r[0] = (short)f2bf(x.x); r[1] = (short)f2bf(x.y);
  r[2] = (short)f2bf(x.z); r[3] = (short)f2bf(x.w);
  r[4] = (short)f2bf(y.x); r[5] = (short)f2bf(y.y);
  r[6] = (short)f2bf(y.z); r[7] = (short)f2bf(y.w);
  return r;
}

__device__ __forceinline__ void gl_lds16(const void* g, void* l) {
  __builtin_amdgcn_global_load_lds(
      (const __attribute__((address_space(1))) unsigned int*)g,
      (__attribute__((address_space(3))) unsigned int*)l, 16, 0, 0);
}

// ---------------- zero / convert / embed ----------------

__global__ void zero_k(uint4* __restrict__ p, int n16) {
  int i = blockIdx.x * blockDim.x + threadIdx.x;
  int stride = gridDim.x * blockDim.x;
  uint4 z = {0u, 0u, 0u, 0u};
  for (; i < n16; i += stride) p[i] = z;
}

__global__ void cvt_bf16_v4(const float4* __restrict__ in, u16x4* __restrict__ out, int n4) {
  int i = blockIdx.x * blockDim.x + threadIdx.x;
  int stride = gridDim.x * blockDim.x;
  for (; i < n4; i += stride) {
    float4 v = in[i];
    u16x4 o;
    o[0] = f2bf(v.x); o[1] = f2bf(v.y); o[2] = f2bf(v.z); o[3] = f2bf(v.w);
    out[i] = o;
  }
}

__global__ __launch_bounds__(256) void embed_k(const int* __restrict__ captions,
                                               const float* __restrict__ etab,
                                               const float* __restrict__ pos,
                                               unsigned short* __restrict__ X) {
  const int m = blockIdx.x;  // row = t*32 + b
  const int t = m >> 5, b = m & 31;
  if (t < TT - 1) {
    const int tok = captions[b * TT + t];
    const float* er = etab + (size_t)tok * EE;
    for (int e = threadIdx.x; e < EE; e += 256)
      X[(size_t)m * EE + e] = f2bf(er[e] + pos[e]);
  } else {
    for (int e = threadIdx.x; e < EE; e += 256) X[(size_t)m * EE + e] = 0;
  }
}

__global__ void zero_out_t0(float* __restrict__ out) {
  out[(size_t)blockIdx.y * TT * VV + blockIdx.x * 256 + threadIdx.x] = 0.f;
}

// ---------------- C = A @ B^T bf16 MFMA GEMM (G0pre only) ----------------

__global__ __launch_bounds__(256) void gemm_bt(const unsigned short* __restrict__ A,
                                               const unsigned short* __restrict__ Bm,
                                               int K, int N,
                                               const float* __restrict__ bias0,
                                               const float* __restrict__ bias1,
                                               float* __restrict__ Cout) {
  __shared__ unsigned short As[128 * 64];
  __shared__ unsigned short Bs[128 * 64];
  const int tid = threadIdx.x;
  const int lane = tid & 63, wave = tid >> 6;
  const int wm = wave & 1, wn = wave >> 1;
  const int nwg = gridDim.x * gridDim.y;
  const int lin = blockIdx.y * gridDim.x + blockIdx.x;
  const int cpx = nwg >> 3;
  const int wg = (lin & 7) * cpx + (lin >> 3);
  const int m0 = (wg % gridDim.x) * 128, n0 = (wg / gridDim.x) * 128;
  const int sch = (lane & 7) * 8;
  const int srbase = wave * 32 + (lane >> 3);
  f32x4 acc[4][4] = {};

  for (int k0 = 0; k0 < K; k0 += 64) {
    __syncthreads();
#pragma unroll
    for (int i = 0; i < 4; ++i) {
      const int r = srbase + i * 8;
      gl_lds16(&A[(size_t)(m0 + r) * K + k0 + sch], &As[(wave * 4 + i) * 512]);
      gl_lds16(&Bm[(size_t)(n0 + r) * K + k0 + sch], &Bs[(wave * 4 + i) * 512]);
    }
    __syncthreads();
#pragma unroll
    for (int kk = 0; kk < 64; kk += 32) {
      s16x8 af[4], bf[4];
#pragma unroll
      for (int f = 0; f < 4; ++f) {
        af[f] = *(const s16x8*)(&As[(wm * 64 + f * 16 + (lane & 15)) * 64 + kk + (lane >> 4) * 8]);
        bf[f] = *(const s16x8*)(&Bs[(wn * 64 + f * 16 + (lane & 15)) * 64 + kk + (lane >> 4) * 8]);
      }
#pragma unroll
      for (int mi = 0; mi < 4; ++mi)
#pragma unroll
        for (int ni = 0; ni < 4; ++ni)
          acc[mi][ni] = MFMA16(af[mi], bf[ni], acc[mi][ni]);
    }
  }

#pragma unroll
  for (int mi = 0; mi < 4; ++mi) {
#pragma unroll
    for (int ni = 0; ni < 4; ++ni) {
      const int col = n0 + wn * 64 + ni * 16 + (lane & 15);
      float bs = bias0[col] + bias1[col];
      const int mbase = m0 + wm * 64 + mi * 16 + (lane >> 4) * 4;
#pragma unroll
      for (int r = 0; r < 4; ++r) {
        int m = mbase + r;
        if (m < MROWS) Cout[(size_t)m * N + col] = acc[mi][ni][r] + bs;
      }
    }
  }
}

// ---------------- persistent LSTM (blocks 0..255) + free-running projection
// workers (blocks 256..511) in ONE dispatch. Workers poll the epoch word
// (read-only) and consume published m-tiles; they never join the barrier.

__global__ __launch_bounds__(256, 1) void lstm_persist(
    const float* __restrict__ Whh0f, const float* __restrict__ Wih1f,
    const float* __restrict__ Whh1f, const float* __restrict__ G0pre,
    const float* __restrict__ bih1, const float* __restrict__ bhh1,
    unsigned short* __restrict__ h0seq, unsigned short* __restrict__ hseq1,
    unsigned short* __restrict__ hs_all,
    const unsigned short* __restrict__ Woutb, const float* __restrict__ bout,
    float* __restrict__ out,
    unsigned int* __restrict__ flags, unsigned int* __restrict__ epoch) {
  __shared__ float parts[4][2][2][16][16];   // 8KB   (recurrence)
  __shared__ unsigned short As[128 * 64];    // 16KB  (worker staging)
  __shared__ unsigned short Bs[128 * 64];    // 16KB
  const int bid = blockIdx.x;
  const int tid = threadIdx.x, lane = tid & 63, wave = tid >> 6;

  // ======================= projection worker role =======================
  if (bid >= NREC) {
    const int w = bid - NREC;
    const unsigned short* hsA = hs_all + BH;  // rows 0..4063 = slots 1..127
    const int wmP = wave & 1, wnP = wave >> 1;
    const int schP = (lane & 7) * 8;
    const int srbaseP = wave * 32 + (lane >> 3);
    volatile unsigned int* ep = &epoch[(bid & 7) * 32];

    for (int lin = w; lin < NTILE; lin += NWRK) {
      const int j = lin / 250, n = lin % 250;
      const unsigned need = (j >= 31) ? 128u : (unsigned)(4 * j + 5);
      if (tid == 0) {
        while (*ep < need) __builtin_amdgcn_s_sleep(8);
      }
      __syncthreads();

      const unsigned short* Ab = hsA + (size_t)j * 128 * HH;
      const unsigned short* Wb = Woutb + (size_t)n * 128 * HH;
      f32x4 pacc[4][4] = {};
      for (int k0 = 0; k0 < HH; k0 += 64) {
        __syncthreads();
#pragma unroll
        for (int i = 0; i < 4; ++i) {
          const int r = srbaseP + i * 8;
          gl_lds16(&Ab[(size_t)r * HH + k0 + schP], &As[(wave * 4 + i) * 512]);
          gl_lds16(&Wb[(size_t)r * HH + k0 + schP], &Bs[(wave * 4 + i) * 512]);
        }
        __syncthreads();
#pragma unroll
        for (int kk = 0; kk < 64; kk += 32) {
          s16x8 af[4], bf[4];
#pragma unroll
          for (int f = 0; f < 4; ++f) {
            af[f] = *(const s16x8*)(&As[(wmP * 64 + f * 16 + (lane & 15)) * 64 + kk + (lane >> 4) * 8]);
            bf[f] = *(const s16x8*)(&Bs[(wnP * 64 + f * 16 + (lane & 15)) * 64 + kk + (lane >> 4) * 8]);
          }
#pragma unroll
          for (int mi = 0; mi < 4; ++mi)
#pragma unroll
            for (int ni = 0; ni < 4; ++ni)
              pacc[mi][ni] = MFMA16(af[mi], bf[ni], pacc[mi][ni]);
        }
      }
      const int m0p = j * 128, n0p = n * 128;
#pragma unroll
      for (int mi = 0; mi < 4; ++mi)
#pragma unroll
        for (int ni = 0; ni < 4; ++ni) {
          const int col = n0p + wnP * 64 + ni * 16 + (lane & 15);
          const float bs = bout[col];
          const int mbase = m0p + wmP * 64 + mi * 16 + (lane >> 4) * 4;
#pragma unroll
          for (int r2 = 0; r2 < 4; ++r2) {
            const int m = mbase + r2;
            if (m < MROWS) {
              const int tt = m >> 5, b2 = m & 31;
              out[((size_t)b2 * TT + tt + 1) * VV + col] = pacc[mi][ni][r2] + bs;
            }
          }
        }
      __syncthreads();
    }
    return;
  }

  // ======================= recurrence role (round-6 verbatim) ============
  const int layer = bid >> 7;
  const int blk = bid & 127;
  const int jb = blk * 8;
  const int colIdx = lane & 15;
  const int kq = lane >> 4;
  const int wrow0 = (colIdx >> 3) * HH + jb + (colIdx & 7);

  const int cb = tid >> 3, cjj = tid & 7;
  float creg = 0.f;
  float bsum[4];
  if (layer == 1) {
#pragma unroll
    for (int gi = 0; gi < 4; ++gi)
      bsum[gi] = bih1[gi * HH + jb + cjj] + bhh1[gi * HH + jb + cjj];
  }

  s16x8 wreg[16][2];
  const int kb = (layer == 0) ? wave * 256 : (wave & 1) * 512;
  if (layer == 0) {
#pragma unroll
    for (int fi = 0; fi < 2; ++fi) {
      const float* wp = Whh0f + (size_t)(wrow0 + fi * 2 * HH) * HH + kb + kq * 8;
#pragma unroll
      for (int ks = 0; ks < 8; ++ks) wreg[ks][fi] = pack8f(wp + ks * 32);
    }
  } else {
    const float* Wsrc = (wave < 2) ? Wih1f : Whh1f;
#pragma unroll
    for (int fi = 0; fi < 2; ++fi) {
      const float* wp = Wsrc + (size_t)(wrow0 + fi * 2 * HH) * HH + kb + kq * 8;
#pragma unroll
      for (int ks = 0; ks < 16; ++ks) wreg[ks][fi] = pack8f(wp + ks * 32);
    }
  }

  const int frag_off = (kb >> 3) * 256 + kq * 256 + (lane & 15) * 8;

  for (int t = 0; t < TT; ++t) {
    if (layer == 0) {
      if (t < TT - 1) {
        float gpre[4];
#pragma unroll
        for (int gi = 0; gi < 4; ++gi)
          gpre[gi] = G0pre[((size_t)t * BB + cb) * FH + gi * HH + jb + cjj];

        const unsigned short* a0 = h0seq + (size_t)t * BH + frag_off;
        const unsigned short* a1 = a0 + 128;
        f32x4 acc00 = {}, acc01 = {}, acc10 = {}, acc11 = {};
#pragma unroll
        for (int ks = 0; ks < 8; ++ks) {
          s16x8 av0 = *(const s16x8*)(a0 + ks * 1024);
          s16x8 av1 = *(const s16x8*)(a1 + ks * 1024);
          acc00 = MFMA16(av0, wreg[ks][0], acc00);
          acc01 = MFMA16(av0, wreg[ks][1], acc01);
          acc10 = MFMA16(av1, wreg[ks][0], acc10);
          acc11 = MFMA16(av1, wreg[ks][1], acc11);
        }
#pragma unroll
        for (int r = 0; r < 4; ++r) {
          parts[wave][0][0][kq * 4 + r][colIdx] = acc00[r];
          parts[wave][0][1][kq * 4 + r][colIdx] = acc01[r];
          parts[wave][1][0][kq * 4 + r][colIdx] = acc10[r];
          parts[wave][1][1][kq * 4 + r][colIdx] = acc11[r];
        }
        __syncthreads();
        float g[4];
#pragma unroll
        for (int gi = 0; gi < 4; ++gi) {
          float s = gpre[gi];
          const int fi = gi >> 1, c = (gi & 1) * 8 + cjj;
#pragma unroll
          for (int w4 = 0; w4 < 4; ++w4) s += parts[w4][cb >> 4][fi][cb & 15][c];
          g[gi] = s;
        }
        const float i_ = sigf(g[0]), f_ = sigf(g[1]), gg = tanhf(g[2]), o_ = sigf(g[3]);
        creg = f_ * creg + i_ * gg;
        *(volatile unsigned short*)&h0seq[(size_t)(t + 1) * BH + blk * 256 + tid] =
            f2bf(o_ * tanhf(creg));
      }
    } else {
      if (t >= 1) {
        const unsigned short* base = (wave < 2)
                                         ? (h0seq + (size_t)t * BH)
                                         : (hseq1 + (size_t)(t - 1) * BH);
        const unsigned short* a0 = base + frag_off;
        const unsigned short* a1 = a0 + 128;
        f32x4 acc00 = {}, acc01 = {}, acc10 = {}, acc11 = {};
#pragma unroll
        for (int ks = 0; ks < 16; ++ks) {
          s16x8 av0 = *(const s16x8*)(a0 + ks * 1024);
          s16x8 av1 = *(const s16x8*)(a1 + ks * 1024);
          acc00 = MFMA16(av0, wreg[ks][0], acc00);
          acc01 = MFMA16(av0, wreg[ks][1], acc01);
          acc10 = MFMA16(av1, wreg[ks][0], acc10);
          acc11 = MFMA16(av1, wreg[ks][1], acc11);
        }
#pragma unroll
        for (int r = 0; r < 4; ++r) {
          parts[wave][0][0][kq * 4 + r][colIdx] = acc00[r];
          parts[wave][0][1][kq * 4 + r][colIdx] = acc01[r];
          parts[wave][1][0][kq * 4 + r][colIdx] = acc10[r];
          parts[wave][1][1][kq * 4 + r][colIdx] = acc11[r];
        }
        __syncthreads();
        float g[4];
#pragma unroll
        for (int gi = 0; gi < 4; ++gi) {
          float s = bsum[gi];
          const int fi = gi >> 1, c = (gi & 1) * 8 + cjj;
#pragma unroll
          for (int w4 = 0; w4 < 4; ++w4) s += parts[w4][cb >> 4][fi][cb & 15][c];
          g[gi] = s;
        }
        const float i_ = sigf(g[0]), f_ = sigf(g[1]), gg = tanhf(g[2]), o_ = sigf(g[3]);
        creg = f_ * creg + i_ * gg;
        const unsigned short hv = f2bf(o_ * tanhf(creg));
        *(volatile unsigned short*)&hseq1[(size_t)t * BH + blk * 256 + tid] = hv;
        *(volatile unsigned short*)&hs_all[(size_t)t * BH + (size_t)cb * HH + jb + cjj] = hv;
      }
    }

    if (t < TT - 1) {
      // barrier: arrival -> (block0) aggregate+epoch -> members poll epoch
      asm volatile("s_waitcnt vmcnt(0)" ::: "memory");
      __syncthreads();
      if (tid == 0) *(volatile unsigned int*)&flags[bid * 32] = (unsigned int)(t + 1);
      const unsigned int target = (unsigned int)(t + 1);
      if (bid == 0) {
        if (tid < 64) {
          for (;;) {
            unsigned a = __hip_atomic_load(&flags[(tid * 4 + 0) * 32], __ATOMIC_RELAXED,
                                           __HIP_MEMORY_SCOPE_AGENT);
            unsigned b = __hip_atomic_load(&flags[(tid * 4 + 1) * 32], __ATOMIC_RELAXED,
                                           __HIP_MEMORY_SCOPE_AGENT);
            unsigned c = __hip_atomic_load(&flags[(tid * 4 + 2) * 32], __ATOMIC_RELAXED,
                                           __HIP_MEMORY_SCOPE_AGENT);
            unsigned d = __hip_atomic_load(&flags[(tid * 4 + 3) * 32], __ATOMIC_RELAXED,
                                           __HIP_MEMORY_SCOPE_AGENT);
            unsigned mn = min(min(a, b), min(c, d));
            if (__all(mn >= target)) break;
            __builtin_amdgcn_s_sleep(1);
          }
          if (tid < 8) *(volatile unsigned int*)&epoch[tid * 32] = target;
        }
      } else if (tid == 0) {
        volatile unsigned int* ep = &epoch[(bid & 7) * 32];
        while (*ep < target) __builtin_amdgcn_s_sleep(2);
      }
      __syncthreads();
      asm volatile("" ::: "memory");
    }
  }

  // final completion publish (epoch=128) so workers can take j=31 tiles
  asm volatile("s_waitcnt vmcnt(0)" ::: "memory");
  __syncthreads();
  if (tid == 0) *(volatile unsigned int*)&flags[bid * 32] = 128u;
  if (bid == 0 && tid < 64) {
    for (;;) {
      unsigned a = __hip_atomic_load(&flags[(tid * 4 + 0) * 32], __ATOMIC_RELAXED,
                                     __HIP_MEMORY_SCOPE_AGENT);
      unsigned b = __hip_atomic_load(&flags[(tid * 4 + 1) * 32], __ATOMIC_RELAXED,
                                     __HIP_MEMORY_SCOPE_AGENT);
      unsigned c = __hip_atomic_load(&flags[(tid * 4 + 2) * 32], __ATOMIC_RELAXED,
                                     __HIP_MEMORY_SCOPE_AGENT);
      unsigned d = __hip_atomic_load(&flags[(tid * 4 + 3) * 32], __ATOMIC_RELAXED,
                                     __HIP_MEMORY_SCOPE_AGENT);
      unsigned mn = min(min(a, b), min(c, d));
      if (__all(mn >= 128u)) break;
      __builtin_amdgcn_s_sleep(1);
    }
    if (tid < 8) *(volatile unsigned int*)&epoch[tid * 32] = 128u;
  }
}

// ---------------- host ----------------

extern "C" void kernel_launch(void* const* d_in, const int* in_sizes, int n_in,
                              void* d_out, int out_size, void* d_ws, size_t ws_size,
                              hipStream_t stream) {
  const int* captions = (const int*)d_in[1];
  const float* etab = (const float*)d_in[2];
  const float* pos = (const float*)d_in[3];
  const float* Wih0 = (const float*)d_in[4];
  const float* Whh0 = (const float*)d_in[5];
  const float* bih0 = (const float*)d_in[6];
  const float* bhh0 = (const float*)d_in[7];
  const float* Wih1 = (const float*)d_in[8];
  const float* Whh1 = (const float*)d_in[9];
  const float* bih1 = (const float*)d_in[10];
  const float* bhh1 = (const float*)d_in[11];
  const float* Wout = (const float*)d_in[12];
  const float* bout = (const float*)d_in[13];
  float* out = (float*)d_out;

  char* w = (char*)d_ws;
  auto alloc = [&](size_t bytes) {
    char* p = w;
    w += (bytes + 255) & ~(size_t)255;
    return p;
  };
  unsigned int* flags = (unsigned int*)alloc((size_t)NREC * 128);
  unsigned int* epoch = (unsigned int*)alloc(1024);
  unsigned short* h0seq = (unsigned short*)alloc((size_t)TT * BH * 2);   // block-major
  unsigned short* hseq1 = (unsigned short*)alloc((size_t)TT * BH * 2);   // block-major
  unsigned short* hs_all = (unsigned short*)alloc((size_t)4160 * HH * 2);// row-major

  unsigned short* Xb = (unsigned short*)alloc((size_t)MPAD * EE * 2);
  unsigned short* Wih0b = (unsigned short*)alloc((size_t)FH * EE * 2);
  unsigned short* Woutb = (unsigned short*)alloc((size_t)VV * HH * 2);
  float* G0pre = (float*)alloc((size_t)MROWS * FH * 4);

  // 1) zero read-before-write state: flags+epoch+h0seq[slot0]; hseq1[slot0]
  const int span0 = (NREC * 128 + 1024 + BH * 2) / 16;
  hipLaunchKernelGGL(zero_k, dim3(25), dim3(256), 0, stream, (uint4*)flags, span0);
  hipLaunchKernelGGL(zero_k, dim3(16), dim3(256), 0, stream, (uint4*)hseq1,
                     (int)((BH * 2) / 16));
  // 2) convert Wih0 / Wout to bf16
  hipLaunchKernelGGL(cvt_bf16_v4, dim3(1024), dim3(256), 0, stream, (const float4*)Wih0,
                     (u16x4*)Wih0b, FH * EE / 4);
  hipLaunchKernelGGL(cvt_bf16_v4, dim3(4096), dim3(256), 0, stream, (const float4*)Wout,
                     (u16x4*)Woutb, VV * HH / 4);
  // 3) embeddings + pos -> X
  hipLaunchKernelGGL(embed_k, dim3(MPAD), dim3(256), 0, stream, captions, etab, pos, Xb);
  // 4) G0pre = X @ Wih0^T + bih0 + bhh0
  hipLaunchKernelGGL(gemm_bt, dim3(32, 32), dim3(256), 0, stream, Xb, Wih0b, EE, FH, bih0,
                     bhh0, G0pre);
  // 5) persistent recurrence (blocks 0..255) + decoupled projection workers
  //    (blocks 256..511), all co-resident (2 blocks/CU)
  hipLaunchKernelGGL(lstm_persist, dim3(NREC + NWRK), dim3(256), 0, stream, Whh0, Wih1, Whh1,
                     G0pre, bih1, bhh1, h0seq, hseq1, hs_all, Woutb, bout, out, flags, epoch);
  // 6) out[:, 0, :] = 0
  hipLaunchKernelGGL(zero_out_t0, dim3(125, 32), dim3(256), 0, stream, out);
}

// Round 10
// 1441.672 us; speedup vs baseline: 1.2574x; 1.2574x over previous
//
#include <hip/hip_runtime.h>
#include <hip/hip_bf16.h>
#include <math.h>

typedef __attribute__((ext_vector_type(4))) float f32x4;
typedef __attribute__((ext_vector_type(8))) short s16x8;
typedef __attribute__((ext_vector_type(4))) unsigned short u16x4;

#define MFMA16(a, b, c) __builtin_amdgcn_mfma_f32_16x16x32_bf16(a, b, c, 0, 0, 0)

static constexpr int BB = 32, TT = 128, EE = 512, HH = 1024, VV = 32000;
static constexpr int FH = 4 * HH;           // 4096 gate rows
static constexpr int MROWS = (TT - 1) * BB; // 4064 valid rows
static constexpr int MPAD = 4096;
static constexpr int BH = BB * HH;          // 32768
static constexpr int NBLK = 256;            // recurrence grid

__device__ __forceinline__ unsigned short f2bf(float f) {
  unsigned int u = __float_as_uint(f);
  u = (u + 0x7FFFu + ((u >> 16) & 1u)) >> 16;
  return (unsigned short)u;
}
__device__ __forceinline__ float sigf(float x) { return 1.f / (1.f + __expf(-x)); }

__device__ __forceinline__ s16x8 pack8f(const float* p) {
  float4 x = *(const float4*)p;
  float4 y = *(const float4*)(p + 4);
  s16x8 r;
  r[0] = (short)f2bf(x.x); r[1] = (short)f2bf(x.y);
  r[2] = (short)f2bf(x.z); r[3] = (short)f2bf(x.w);
  r[4] = (short)f2bf(y.x); r[5] = (short)f2bf(y.y);
  r[6] = (short)f2bf(y.z); r[7] = (short)f2bf(y.w);
  return r;
}

__device__ __forceinline__ void gl_lds16(const void* g, void* l) {
  __builtin_amdgcn_global_load_lds(
      (const __attribute__((address_space(1))) unsigned int*)g,
      (__attribute__((address_space(3))) unsigned int*)l, 16, 0, 0);
}

// ---------------- zero / convert / embed ----------------

__global__ void zero_k(uint4* __restrict__ p, int n16) {
  int i = blockIdx.x * blockDim.x + threadIdx.x;
  int stride = gridDim.x * blockDim.x;
  uint4 z = {0u, 0u, 0u, 0u};
  for (; i < n16; i += stride) p[i] = z;
}

__global__ void cvt_bf16_v4(const float4* __restrict__ in, u16x4* __restrict__ out, int n4) {
  int i = blockIdx.x * blockDim.x + threadIdx.x;
  int stride = gridDim.x * blockDim.x;
  for (; i < n4; i += stride) {
    float4 v = in[i];
    u16x4 o;
    o[0] = f2bf(v.x); o[1] = f2bf(v.y); o[2] = f2bf(v.z); o[3] = f2bf(v.w);
    out[i] = o;
  }
}

__global__ __launch_bounds__(256) void embed_k(const int* __restrict__ captions,
                                               const float* __restrict__ etab,
                                               const float* __restrict__ pos,
                                               unsigned short* __restrict__ X) {
  const int m = blockIdx.x;  // row = t*32 + b
  const int t = m >> 5, b = m & 31;
  if (t < TT - 1) {
    const int tok = captions[b * TT + t];
    const float* er = etab + (size_t)tok * EE;
    for (int e = threadIdx.x; e < EE; e += 256)
      X[(size_t)m * EE + e] = f2bf(er[e] + pos[e]);
  } else {
    for (int e = threadIdx.x; e < EE; e += 256) X[(size_t)m * EE + e] = 0;
  }
}

__global__ void zero_out_t0(float* __restrict__ out) {
  out[(size_t)blockIdx.y * TT * VV + blockIdx.x * 256 + threadIdx.x] = 0.f;
}

// ---------------- G0pre GEMM (C = A @ B^T + b0 + b1), m97 staging ----------

__global__ __launch_bounds__(256) void gemm_bt(const unsigned short* __restrict__ A,
                                               const unsigned short* __restrict__ Bm,
                                               int K, int N,
                                               const float* __restrict__ bias0,
                                               const float* __restrict__ bias1,
                                               float* __restrict__ Cout) {
  __shared__ unsigned short As[128 * 64];
  __shared__ unsigned short Bs[128 * 64];
  const int tid = threadIdx.x;
  const int lane = tid & 63, wave = tid >> 6;
  const int wm = wave & 1, wn = wave >> 1;
  const int m0 = blockIdx.x * 128, n0 = blockIdx.y * 128;
  const int sch = (lane & 7) * 8;
  const int srbase = wave * 32 + (lane >> 3);
  f32x4 acc[4][4] = {};

  for (int k0 = 0; k0 < K; k0 += 64) {
    __syncthreads();
#pragma unroll
    for (int i = 0; i < 4; ++i) {
      const int r = srbase + i * 8;
      gl_lds16(&A[(size_t)(m0 + r) * K + k0 + sch], &As[(wave * 4 + i) * 512]);
      gl_lds16(&Bm[(size_t)(n0 + r) * K + k0 + sch], &Bs[(wave * 4 + i) * 512]);
    }
    __syncthreads();
#pragma unroll
    for (int kk = 0; kk < 64; kk += 32) {
      s16x8 af[4], bf[4];
#pragma unroll
      for (int f = 0; f < 4; ++f) {
        af[f] = *(const s16x8*)(&As[(wm * 64 + f * 16 + (lane & 15)) * 64 + kk + (lane >> 4) * 8]);
        bf[f] = *(const s16x8*)(&Bs[(wn * 64 + f * 16 + (lane & 15)) * 64 + kk + (lane >> 4) * 8]);
      }
#pragma unroll
      for (int mi = 0; mi < 4; ++mi)
#pragma unroll
        for (int ni = 0; ni < 4; ++ni)
          acc[mi][ni] = MFMA16(af[mi], bf[ni], acc[mi][ni]);
    }
  }

#pragma unroll
  for (int mi = 0; mi < 4; ++mi) {
#pragma unroll
    for (int ni = 0; ni < 4; ++ni) {
      const int col = n0 + wn * 64 + ni * 16 + (lane & 15);
      float bs = bias0[col] + bias1[col];
      const int mbase = m0 + wm * 64 + mi * 16 + (lane >> 4) * 4;
#pragma unroll
      for (int r = 0; r < 4; ++r) {
        int m = mbase + r;
        if (m < MROWS) Cout[(size_t)m * N + col] = acc[mi][ni][r] + bs;
      }
    }
  }
}

// ---------------- projection GEMM with XCD-compact supertile order --------
// 1-D grid of 8000 blocks. T = ng*64 + j*2 + dn ; n = 2*ng + dn ; m-tile j.
// With HW round-robin (XCD = T%8): each XCD keeps its 8 A-panels L2-resident
// for the whole run; each B-panel is fetched by only 4 XCDs.

__global__ __launch_bounds__(256) void proj_gemm(const unsigned short* __restrict__ hsA,
                                                 const unsigned short* __restrict__ Woutb,
                                                 const float* __restrict__ bout,
                                                 float* __restrict__ out) {
  __shared__ unsigned short As[128 * 64];
  __shared__ unsigned short Bs[128 * 64];
  const int tid = threadIdx.x;
  const int lane = tid & 63, wave = tid >> 6;
  const int wm = wave & 1, wn = wave >> 1;
  const int T = blockIdx.x;
  const int ng = T >> 6, r6 = T & 63;
  const int j = r6 >> 1, dn = r6 & 1;
  const int n = ng * 2 + dn;
  const int m0 = j * 128, n0 = n * 128;
  const int sch = (lane & 7) * 8;
  const int srbase = wave * 32 + (lane >> 3);
  f32x4 acc[4][4] = {};

  for (int k0 = 0; k0 < HH; k0 += 64) {
    __syncthreads();
#pragma unroll
    for (int i = 0; i < 4; ++i) {
      const int rr = srbase + i * 8;
      gl_lds16(&hsA[(size_t)(m0 + rr) * HH + k0 + sch], &As[(wave * 4 + i) * 512]);
      gl_lds16(&Woutb[(size_t)(n0 + rr) * HH + k0 + sch], &Bs[(wave * 4 + i) * 512]);
    }
    __syncthreads();
#pragma unroll
    for (int kk = 0; kk < 64; kk += 32) {
      s16x8 af[4], bf[4];
#pragma unroll
      for (int f = 0; f < 4; ++f) {
        af[f] = *(const s16x8*)(&As[(wm * 64 + f * 16 + (lane & 15)) * 64 + kk + (lane >> 4) * 8]);
        bf[f] = *(const s16x8*)(&Bs[(wn * 64 + f * 16 + (lane & 15)) * 64 + kk + (lane >> 4) * 8]);
      }
#pragma unroll
      for (int mi = 0; mi < 4; ++mi)
#pragma unroll
        for (int ni = 0; ni < 4; ++ni)
          acc[mi][ni] = MFMA16(af[mi], bf[ni], acc[mi][ni]);
    }
  }

#pragma unroll
  for (int mi = 0; mi < 4; ++mi) {
#pragma unroll
    for (int ni = 0; ni < 4; ++ni) {
      const int col = n0 + wn * 64 + ni * 16 + (lane & 15);
      const float bs = bout[col];
      const int mbase = m0 + wm * 64 + mi * 16 + (lane >> 4) * 4;
#pragma unroll
      for (int r2 = 0; r2 < 4; ++r2) {
        const int m = mbase + r2;
        if (m < MROWS) {
          const int tt = m >> 5, b2 = m & 31;
          out[((size_t)b2 * TT + tt + 1) * VV + col] = acc[mi][ni][r2] + bs;
        }
      }
    }
  }
}

// ---------------- persistent 2-layer LSTM, SPLIT per-layer barriers -------
// L0 (blocks 0..127): chain gated only by its own 128-block flag/epoch
// (aggregator block 0). L1 (blocks 128..255): gated on epoch0[t] (data dep,
// L0 runs ahead so usually satisfied) + its own epoch1 (aggregator block 128).

__global__ __launch_bounds__(256, 1) void lstm_persist(
    const float* __restrict__ Whh0f, const float* __restrict__ Wih1f,
    const float* __restrict__ Whh1f, const float* __restrict__ G0pre,
    const float* __restrict__ bih1, const float* __restrict__ bhh1,
    unsigned short* __restrict__ h0seq, unsigned short* __restrict__ hseq1,
    unsigned short* __restrict__ hs_all,
    unsigned int* __restrict__ flags0, unsigned int* __restrict__ flags1,
    unsigned int* __restrict__ epoch0, unsigned int* __restrict__ epoch1) {
  __shared__ float parts[4][2][2][16][16];  // 8KB
  const int bid = blockIdx.x;
  const int layer = bid >> 7;
  const int blk = bid & 127;
  const int tid = threadIdx.x, lane = tid & 63, wave = tid >> 6;
  const int jb = blk * 8;
  const int colIdx = lane & 15;
  const int kq = lane >> 4;
  const int wrow0 = (colIdx >> 3) * HH + jb + (colIdx & 7);

  const int cb = tid >> 3, cjj = tid & 7;
  float creg = 0.f;
  float bsum[4];
  if (layer == 1) {
#pragma unroll
    for (int gi = 0; gi < 4; ++gi)
      bsum[gi] = bih1[gi * HH + jb + cjj] + bhh1[gi * HH + jb + cjj];
  }

  // ---- recurrent weights into registers (fp32 -> bf16) ----
  s16x8 wreg[16][2];
  const int kb = (layer == 0) ? wave * 256 : (wave & 1) * 512;
  if (layer == 0) {
#pragma unroll
    for (int fi = 0; fi < 2; ++fi) {
      const float* wp = Whh0f + (size_t)(wrow0 + fi * 2 * HH) * HH + kb + kq * 8;
#pragma unroll
      for (int ks = 0; ks < 8; ++ks) wreg[ks][fi] = pack8f(wp + ks * 32);
    }
  } else {
    const float* Wsrc = (wave < 2) ? Wih1f : Whh1f;
#pragma unroll
    for (int fi = 0; fi < 2; ++fi) {
      const float* wp = Wsrc + (size_t)(wrow0 + fi * 2 * HH) * HH + kb + kq * 8;
#pragma unroll
      for (int ks = 0; ks < 16; ++ks) wreg[ks][fi] = pack8f(wp + ks * 32);
    }
  }

  const int frag_off = (kb >> 3) * 256 + kq * 256 + (lane & 15) * 8;

  if (layer == 0) {
    // =================== L0 chain ===================
    volatile unsigned int* ep0 = &epoch0[(bid & 7) * 32];
    for (int t = 0; t < TT - 1; ++t) {
      // gpre prefetch (independent of the epoch gate)
      float gpre[4];
#pragma unroll
      for (int gi = 0; gi < 4; ++gi)
        gpre[gi] = G0pre[((size_t)t * BB + cb) * FH + gi * HH + jb + cjj];

      if (t > 0 && tid == 0) {
        while (*ep0 < (unsigned)t) __builtin_amdgcn_s_sleep(2);
      }
      __syncthreads();
      asm volatile("" ::: "memory");

      const unsigned short* a0 = h0seq + (size_t)t * BH + frag_off;
      const unsigned short* a1 = a0 + 128;
      f32x4 acc00 = {}, acc01 = {}, acc10 = {}, acc11 = {};
#pragma unroll
      for (int ks = 0; ks < 8; ++ks) {
        s16x8 av0 = *(const s16x8*)(a0 + ks * 1024);
        s16x8 av1 = *(const s16x8*)(a1 + ks * 1024);
        acc00 = MFMA16(av0, wreg[ks][0], acc00);
        acc01 = MFMA16(av0, wreg[ks][1], acc01);
        acc10 = MFMA16(av1, wreg[ks][0], acc10);
        acc11 = MFMA16(av1, wreg[ks][1], acc11);
      }
#pragma unroll
      for (int r = 0; r < 4; ++r) {
        parts[wave][0][0][kq * 4 + r][colIdx] = acc00[r];
        parts[wave][0][1][kq * 4 + r][colIdx] = acc01[r];
        parts[wave][1][0][kq * 4 + r][colIdx] = acc10[r];
        parts[wave][1][1][kq * 4 + r][colIdx] = acc11[r];
      }
      __syncthreads();
      float g[4];
#pragma unroll
      for (int gi = 0; gi < 4; ++gi) {
        float s = gpre[gi];
        const int fi = gi >> 1, c = (gi & 1) * 8 + cjj;
#pragma unroll
        for (int w4 = 0; w4 < 4; ++w4) s += parts[w4][cb >> 4][fi][cb & 15][c];
        g[gi] = s;
      }
      const float i_ = sigf(g[0]), f_ = sigf(g[1]), gg = tanhf(g[2]), o_ = sigf(g[3]);
      creg = f_ * creg + i_ * gg;
      *(volatile unsigned short*)&h0seq[(size_t)(t + 1) * BH + blk * 256 + tid] =
          f2bf(o_ * tanhf(creg));

      asm volatile("s_waitcnt vmcnt(0)" ::: "memory");
      __syncthreads();
      if (tid == 0) *(volatile unsigned int*)&flags0[blk * 32] = (unsigned)(t + 1);
      if (bid == 0) {
        if (tid < 64) {
          const unsigned tgt = (unsigned)(t + 1);
          for (;;) {
            unsigned a = __hip_atomic_load(&flags0[(tid * 2 + 0) * 32], __ATOMIC_RELAXED,
                                           __HIP_MEMORY_SCOPE_AGENT);
            unsigned b = __hip_atomic_load(&flags0[(tid * 2 + 1) * 32], __ATOMIC_RELAXED,
                                           __HIP_MEMORY_SCOPE_AGENT);
            if (__all(min(a, b) >= tgt)) break;
            __builtin_amdgcn_s_sleep(1);
          }
          if (tid < 8) *(volatile unsigned int*)&epoch0[tid * 32] = tgt;
        }
        __syncthreads();
      }
    }
  } else {
    // =================== L1 chain ===================
    volatile unsigned int* ep0 = &epoch0[(bid & 7) * 32];
    volatile unsigned int* ep1 = &epoch1[(bid & 7) * 32];
    for (int t = 1; t < TT; ++t) {
      if (tid == 0) {
        while (*ep0 < (unsigned)t) __builtin_amdgcn_s_sleep(2);
        while (*ep1 < (unsigned)(t - 1)) __builtin_amdgcn_s_sleep(2);
      }
      __syncthreads();
      asm volatile("" ::: "memory");

      const unsigned short* base = (wave < 2)
                                       ? (h0seq + (size_t)t * BH)         // h0(t-1)
                                       : (hseq1 + (size_t)(t - 1) * BH);  // h1(t-2)
      const unsigned short* a0 = base + frag_off;
      const unsigned short* a1 = a0 + 128;
      f32x4 acc00 = {}, acc01 = {}, acc10 = {}, acc11 = {};
#pragma unroll
      for (int ks = 0; ks < 16; ++ks) {
        s16x8 av0 = *(const s16x8*)(a0 + ks * 1024);
        s16x8 av1 = *(const s16x8*)(a1 + ks * 1024);
        acc00 = MFMA16(av0, wreg[ks][0], acc00);
        acc01 = MFMA16(av0, wreg[ks][1], acc01);
        acc10 = MFMA16(av1, wreg[ks][0], acc10);
        acc11 = MFMA16(av1, wreg[ks][1], acc11);
      }
#pragma unroll
      for (int r = 0; r < 4; ++r) {
        parts[wave][0][0][kq * 4 + r][colIdx] = acc00[r];
        parts[wave][0][1][kq * 4 + r][colIdx] = acc01[r];
        parts[wave][1][0][kq * 4 + r][colIdx] = acc10[r];
        parts[wave][1][1][kq * 4 + r][colIdx] = acc11[r];
      }
      __syncthreads();
      float g[4];
#pragma unroll
      for (int gi = 0; gi < 4; ++gi) {
        float s = bsum[gi];
        const int fi = gi >> 1, c = (gi & 1) * 8 + cjj;
#pragma unroll
        for (int w4 = 0; w4 < 4; ++w4) s += parts[w4][cb >> 4][fi][cb & 15][c];
        g[gi] = s;
      }
      const float i_ = sigf(g[0]), f_ = sigf(g[1]), gg = tanhf(g[2]), o_ = sigf(g[3]);
      creg = f_ * creg + i_ * gg;
      const unsigned short hv = f2bf(o_ * tanhf(creg));
      *(volatile unsigned short*)&hseq1[(size_t)t * BH + blk * 256 + tid] = hv;
      hs_all[(size_t)t * BH + (size_t)cb * HH + jb + cjj] = hv;  // plain (GEMM copy)

      asm volatile("s_waitcnt vmcnt(0)" ::: "memory");
      __syncthreads();
      if (tid == 0) *(volatile unsigned int*)&flags1[blk * 32] = (unsigned)t;
      if (bid == 128) {
        if (tid < 64) {
          const unsigned tgt = (unsigned)t;
          for (;;) {
            unsigned a = __hip_atomic_load(&flags1[(tid * 2 + 0) * 32], __ATOMIC_RELAXED,
                                           __HIP_MEMORY_SCOPE_AGENT);
            unsigned b = __hip_atomic_load(&flags1[(tid * 2 + 1) * 32], __ATOMIC_RELAXED,
                                           __HIP_MEMORY_SCOPE_AGENT);
            if (__all(min(a, b) >= tgt)) break;
            __builtin_amdgcn_s_sleep(1);
          }
          if (tid < 8) *(volatile unsigned int*)&epoch1[tid * 32] = tgt;
        }
        __syncthreads();
      }
    }
  }
}

// ---------------- host ----------------

extern "C" void kernel_launch(void* const* d_in, const int* in_sizes, int n_in,
                              void* d_out, int out_size, void* d_ws, size_t ws_size,
                              hipStream_t stream) {
  const int* captions = (const int*)d_in[1];
  const float* etab = (const float*)d_in[2];
  const float* pos = (const float*)d_in[3];
  const float* Wih0 = (const float*)d_in[4];
  const float* Whh0 = (const float*)d_in[5];
  const float* bih0 = (const float*)d_in[6];
  const float* bhh0 = (const float*)d_in[7];
  const float* Wih1 = (const float*)d_in[8];
  const float* Whh1 = (const float*)d_in[9];
  const float* bih1 = (const float*)d_in[10];
  const float* bhh1 = (const float*)d_in[11];
  const float* Wout = (const float*)d_in[12];
  const float* bout = (const float*)d_in[13];
  float* out = (float*)d_out;

  char* w = (char*)d_ws;
  auto alloc = [&](size_t bytes) {
    char* p = w;
    w += (bytes + 255) & ~(size_t)255;
    return p;
  };
  // layout: flags0(16KB) flags1(16KB) epoch0(1KB) epoch1(1KB) h0seq hseq1 hs_all ...
  unsigned int* flags0 = (unsigned int*)alloc(128 * 128);
  unsigned int* flags1 = (unsigned int*)alloc(128 * 128);
  unsigned int* epoch0 = (unsigned int*)alloc(1024);
  unsigned int* epoch1 = (unsigned int*)alloc(1024);
  unsigned short* h0seq = (unsigned short*)alloc((size_t)TT * BH * 2);   // block-major
  unsigned short* hseq1 = (unsigned short*)alloc((size_t)TT * BH * 2);   // block-major
  unsigned short* hs_all = (unsigned short*)alloc((size_t)4160 * HH * 2);// row-major

  unsigned short* Xb = (unsigned short*)alloc((size_t)MPAD * EE * 2);
  unsigned short* Wih0b = (unsigned short*)alloc((size_t)FH * EE * 2);
  unsigned short* Woutb = (unsigned short*)alloc((size_t)VV * HH * 2);
  float* G0pre = (float*)alloc((size_t)MROWS * FH * 4);

  // 1) zero read-before-write state: flags0+flags1+epoch0+epoch1+h0seq[slot0]
  //    (contiguous) and hseq1[slot0]
  const int span0 = (128 * 128 * 2 + 2048 + BH * 2) / 16;
  hipLaunchKernelGGL(zero_k, dim3(25), dim3(256), 0, stream, (uint4*)flags0, span0);
  hipLaunchKernelGGL(zero_k, dim3(16), dim3(256), 0, stream, (uint4*)hseq1,
                     (int)((BH * 2) / 16));
  // 2) convert Wih0 / Wout to bf16
  hipLaunchKernelGGL(cvt_bf16_v4, dim3(1024), dim3(256), 0, stream, (const float4*)Wih0,
                     (u16x4*)Wih0b, FH * EE / 4);
  hipLaunchKernelGGL(cvt_bf16_v4, dim3(4096), dim3(256), 0, stream, (const float4*)Wout,
                     (u16x4*)Woutb, VV * HH / 4);
  // 3) embeddings + pos -> X
  hipLaunchKernelGGL(embed_k, dim3(MPAD), dim3(256), 0, stream, captions, etab, pos, Xb);
  // 4) G0pre = X @ Wih0^T + bih0 + bhh0
  hipLaunchKernelGGL(gemm_bt, dim3(32, 32), dim3(256), 0, stream, Xb, Wih0b, EE, FH, bih0,
                     bhh0, G0pre);
  // 5) persistent recurrence, split per-layer barriers
  hipLaunchKernelGGL(lstm_persist, dim3(NBLK), dim3(256), 0, stream, Whh0, Wih1, Whh1, G0pre,
                     bih1, bhh1, h0seq, hseq1, hs_all, flags0, flags1, epoch0, epoch1);
  // 6) projection with XCD-compact supertile ordering
  hipLaunchKernelGGL(proj_gemm, dim3(8000), dim3(256), 0, stream, hs_all + (size_t)BH, Woutb,
                     bout, out);
  // 7) out[:, 0, :] = 0
  hipLaunchKernelGGL(zero_out_t0, dim3(125, 32), dim3(256), 0, stream, out);
}

// Round 11
// 1366.521 us; speedup vs baseline: 1.3265x; 1.0550x over previous
//
#include <hip/hip_runtime.h>
#include <hip/hip_bf16.h>
#include <math.h>

typedef __attribute__((ext_vector_type(4))) float f32x4;
typedef __attribute__((ext_vector_type(8))) short s16x8;
typedef __attribute__((ext_vector_type(4))) unsigned short u16x4;

#define MFMA16(a, b, c) __builtin_amdgcn_mfma_f32_16x16x32_bf16(a, b, c, 0, 0, 0)

static constexpr int BB = 32, TT = 128, EE = 512, HH = 1024, VV = 32000;
static constexpr int FH = 4 * HH;           // 4096 gate rows
static constexpr int MROWS = (TT - 1) * BB; // 4064 valid rows
static constexpr int MPAD = 4096;
static constexpr int BH = BB * HH;          // 32768
static constexpr int NBLK = 256;            // recurrence grid

__device__ __forceinline__ unsigned short f2bf(float f) {
  unsigned int u = __float_as_uint(f);
  u = (u + 0x7FFFu + ((u >> 16) & 1u)) >> 16;
  return (unsigned short)u;
}
__device__ __forceinline__ float sigf(float x) { return 1.f / (1.f + __expf(-x)); }

__device__ __forceinline__ s16x8 pack8f(const float* p) {
  float4 x = *(const float4*)p;
  float4 y = *(const float4*)(p + 4);
  s16x8 r;
  r[0] = (short)f2bf(x.x); r[1] = (short)f2bf(x.y);
  r[2] = (short)f2bf(x.z); r[3] = (short)f2bf(x.w);
  r[4] = (short)f2bf(y.x); r[5] = (short)f2bf(y.y);
  r[6] = (short)f2bf(y.z); r[7] = (short)f2bf(y.w);
  return r;
}

__device__ __forceinline__ void gl_lds16(const void* g, void* l) {
  __builtin_amdgcn_global_load_lds(
      (const __attribute__((address_space(1))) unsigned int*)g,
      (__attribute__((address_space(3))) unsigned int*)l, 16, 0, 0);
}

__device__ __forceinline__ unsigned ldflag(const unsigned int* p) {
  return __hip_atomic_load(p, __ATOMIC_RELAXED, __HIP_MEMORY_SCOPE_AGENT);
}

// ---------------- zero / convert / embed ----------------

__global__ void zero2_k(uint4* __restrict__ p0, int n0, uint4* __restrict__ p1, int n1) {
  int i = blockIdx.x * blockDim.x + threadIdx.x;
  int stride = gridDim.x * blockDim.x;
  uint4 z = {0u, 0u, 0u, 0u};
  for (int k = i; k < n0; k += stride) p0[k] = z;
  for (int k = i; k < n1; k += stride) p1[k] = z;
}

__global__ void cvt2_k(const float4* __restrict__ a, u16x4* __restrict__ ao, int na4,
                       const float4* __restrict__ b, u16x4* __restrict__ bo, int nb4) {
  int i = blockIdx.x * blockDim.x + threadIdx.x;
  int stride = gridDim.x * blockDim.x;
  for (int k = i; k < na4; k += stride) {
    float4 v = a[k];
    u16x4 o;
    o[0] = f2bf(v.x); o[1] = f2bf(v.y); o[2] = f2bf(v.z); o[3] = f2bf(v.w);
    ao[k] = o;
  }
  for (int k = i; k < nb4; k += stride) {
    float4 v = b[k];
    u16x4 o;
    o[0] = f2bf(v.x); o[1] = f2bf(v.y); o[2] = f2bf(v.z); o[3] = f2bf(v.w);
    bo[k] = o;
  }
}

__global__ __launch_bounds__(256) void embed_k(const int* __restrict__ captions,
                                               const float* __restrict__ etab,
                                               const float* __restrict__ pos,
                                               unsigned short* __restrict__ X) {
  const int m = blockIdx.x;  // row = t*32 + b
  const int t = m >> 5, b = m & 31;
  if (t < TT - 1) {
    const int tok = captions[b * TT + t];
    const float* er = etab + (size_t)tok * EE;
    for (int e = threadIdx.x; e < EE; e += 256)
      X[(size_t)m * EE + e] = f2bf(er[e] + pos[e]);
  } else {
    for (int e = threadIdx.x; e < EE; e += 256) X[(size_t)m * EE + e] = 0;
  }
}

__global__ void zero_out_t0(float* __restrict__ out) {
  out[(size_t)blockIdx.y * TT * VV + blockIdx.x * 256 + threadIdx.x] = 0.f;
}

// ---------------- G0pre GEMM (C = A @ B^T + b0 + b1), m97 staging ----------

__global__ __launch_bounds__(256) void gemm_bt(const unsigned short* __restrict__ A,
                                               const unsigned short* __restrict__ Bm,
                                               int K, int N,
                                               const float* __restrict__ bias0,
                                               const float* __restrict__ bias1,
                                               float* __restrict__ Cout) {
  __shared__ unsigned short As[128 * 64];
  __shared__ unsigned short Bs[128 * 64];
  const int tid = threadIdx.x;
  const int lane = tid & 63, wave = tid >> 6;
  const int wm = wave & 1, wn = wave >> 1;
  const int m0 = blockIdx.x * 128, n0 = blockIdx.y * 128;
  const int sch = (lane & 7) * 8;
  const int srbase = wave * 32 + (lane >> 3);
  f32x4 acc[4][4] = {};

  for (int k0 = 0; k0 < K; k0 += 64) {
    __syncthreads();
#pragma unroll
    for (int i = 0; i < 4; ++i) {
      const int r = srbase + i * 8;
      gl_lds16(&A[(size_t)(m0 + r) * K + k0 + sch], &As[(wave * 4 + i) * 512]);
      gl_lds16(&Bm[(size_t)(n0 + r) * K + k0 + sch], &Bs[(wave * 4 + i) * 512]);
    }
    __syncthreads();
#pragma unroll
    for (int kk = 0; kk < 64; kk += 32) {
      s16x8 af[4], bf[4];
#pragma unroll
      for (int f = 0; f < 4; ++f) {
        af[f] = *(const s16x8*)(&As[(wm * 64 + f * 16 + (lane & 15)) * 64 + kk + (lane >> 4) * 8]);
        bf[f] = *(const s16x8*)(&Bs[(wn * 64 + f * 16 + (lane & 15)) * 64 + kk + (lane >> 4) * 8]);
      }
#pragma unroll
      for (int mi = 0; mi < 4; ++mi)
#pragma unroll
        for (int ni = 0; ni < 4; ++ni)
          acc[mi][ni] = MFMA16(af[mi], bf[ni], acc[mi][ni]);
    }
  }

#pragma unroll
  for (int mi = 0; mi < 4; ++mi) {
#pragma unroll
    for (int ni = 0; ni < 4; ++ni) {
      const int col = n0 + wn * 64 + ni * 16 + (lane & 15);
      float bs = bias0[col] + bias1[col];
      const int mbase = m0 + wm * 64 + mi * 16 + (lane >> 4) * 4;
#pragma unroll
      for (int r = 0; r < 4; ++r) {
        int m = mbase + r;
        if (m < MROWS) Cout[(size_t)m * N + col] = acc[mi][ni][r] + bs;
      }
    }
  }
}

// ---------------- projection GEMM, j-major ordering -----------------------
// T = j*250 + n. Concurrent window (~1024 blocks) spans ~4 j-stripes ->
// per-XCD live A-set ~4MB (L2-fit); B becomes IC-resident after stripe 0.

__global__ __launch_bounds__(256) void proj_gemm(const unsigned short* __restrict__ hsA,
                                                 const unsigned short* __restrict__ Woutb,
                                                 const float* __restrict__ bout,
                                                 float* __restrict__ out) {
  __shared__ unsigned short As[128 * 64];
  __shared__ unsigned short Bs[128 * 64];
  const int tid = threadIdx.x;
  const int lane = tid & 63, wave = tid >> 6;
  const int wm = wave & 1, wn = wave >> 1;
  const int T = blockIdx.x;
  const int j = T / 250, n = T % 250;
  const int m0 = j * 128, n0 = n * 128;
  const int sch = (lane & 7) * 8;
  const int srbase = wave * 32 + (lane >> 3);
  f32x4 acc[4][4] = {};

  for (int k0 = 0; k0 < HH; k0 += 64) {
    __syncthreads();
#pragma unroll
    for (int i = 0; i < 4; ++i) {
      const int rr = srbase + i * 8;
      gl_lds16(&hsA[(size_t)(m0 + rr) * HH + k0 + sch], &As[(wave * 4 + i) * 512]);
      gl_lds16(&Woutb[(size_t)(n0 + rr) * HH + k0 + sch], &Bs[(wave * 4 + i) * 512]);
    }
    __syncthreads();
#pragma unroll
    for (int kk = 0; kk < 64; kk += 32) {
      s16x8 af[4], bf[4];
#pragma unroll
      for (int f = 0; f < 4; ++f) {
        af[f] = *(const s16x8*)(&As[(wm * 64 + f * 16 + (lane & 15)) * 64 + kk + (lane >> 4) * 8]);
        bf[f] = *(const s16x8*)(&Bs[(wn * 64 + f * 16 + (lane & 15)) * 64 + kk + (lane >> 4) * 8]);
      }
#pragma unroll
      for (int mi = 0; mi < 4; ++mi)
#pragma unroll
        for (int ni = 0; ni < 4; ++ni)
          acc[mi][ni] = MFMA16(af[mi], bf[ni], acc[mi][ni]);
    }
  }

#pragma unroll
  for (int mi = 0; mi < 4; ++mi) {
#pragma unroll
    for (int ni = 0; ni < 4; ++ni) {
      const int col = n0 + wn * 64 + ni * 16 + (lane & 15);
      const float bs = bout[col];
      const int mbase = m0 + wm * 64 + mi * 16 + (lane >> 4) * 4;
#pragma unroll
      for (int r2 = 0; r2 < 4; ++r2) {
        const int m = mbase + r2;
        if (m < MROWS) {
          const int tt = m >> 5, b2 = m & 31;
          out[((size_t)b2 * TT + tt + 1) * VV + col] = acc[mi][ni][r2] + bs;
        }
      }
    }
  }
}

// ---------------- persistent 2-layer LSTM, flat direct-poll barriers ------
// Per-layer 128-slot flag arrays (128B stride). After publishing h, each block
// stores its own flag; wave 0 then polls ALL own-layer flags directly
// (64 lanes x 2 relaxed atomic loads, __all(min >= target)) — no aggregator,
// no epoch broadcast: one detection round-trip instead of three.

__global__ __launch_bounds__(256, 1) void lstm_persist(
    const float* __restrict__ Whh0f, const float* __restrict__ Wih1f,
    const float* __restrict__ Whh1f, const float* __restrict__ G0pre,
    const float* __restrict__ bih1, const float* __restrict__ bhh1,
    unsigned short* __restrict__ h0seq, unsigned short* __restrict__ hseq1,
    unsigned short* __restrict__ hs_all,
    unsigned int* __restrict__ flags0, unsigned int* __restrict__ flags1) {
  __shared__ float parts[4][2][2][16][16];  // 8KB
  const int bid = blockIdx.x;
  const int layer = bid >> 7;
  const int blk = bid & 127;
  const int tid = threadIdx.x, lane = tid & 63, wave = tid >> 6;
  const int jb = blk * 8;
  const int colIdx = lane & 15;
  const int kq = lane >> 4;
  const int wrow0 = (colIdx >> 3) * HH + jb + (colIdx & 7);

  const int cb = tid >> 3, cjj = tid & 7;
  float creg = 0.f;
  float bsum[4];
  if (layer == 1) {
#pragma unroll
    for (int gi = 0; gi < 4; ++gi)
      bsum[gi] = bih1[gi * HH + jb + cjj] + bhh1[gi * HH + jb + cjj];
  }

  // ---- recurrent weights into registers (fp32 -> bf16) ----
  s16x8 wreg[16][2];
  const int kb = (layer == 0) ? wave * 256 : (wave & 1) * 512;
  if (layer == 0) {
#pragma unroll
    for (int fi = 0; fi < 2; ++fi) {
      const float* wp = Whh0f + (size_t)(wrow0 + fi * 2 * HH) * HH + kb + kq * 8;
#pragma unroll
      for (int ks = 0; ks < 8; ++ks) wreg[ks][fi] = pack8f(wp + ks * 32);
    }
  } else {
    const float* Wsrc = (wave < 2) ? Wih1f : Whh1f;
#pragma unroll
    for (int fi = 0; fi < 2; ++fi) {
      const float* wp = Wsrc + (size_t)(wrow0 + fi * 2 * HH) * HH + kb + kq * 8;
#pragma unroll
      for (int ks = 0; ks < 16; ++ks) wreg[ks][fi] = pack8f(wp + ks * 32);
    }
  }

  const int frag_off = (kb >> 3) * 256 + kq * 256 + (lane & 15) * 8;

  if (layer == 0) {
    // =================== L0 chain ===================
    for (int t = 0; t < TT - 1; ++t) {
      float gpre[4];
#pragma unroll
      for (int gi = 0; gi < 4; ++gi)
        gpre[gi] = G0pre[((size_t)t * BB + cb) * FH + gi * HH + jb + cjj];

      if (t > 0 && wave == 0) {
        const unsigned tgt = (unsigned)t;
        for (;;) {
          unsigned a = ldflag(&flags0[(lane * 2 + 0) * 32]);
          unsigned b = ldflag(&flags0[(lane * 2 + 1) * 32]);
          if (__all(min(a, b) >= tgt)) break;
          __builtin_amdgcn_s_sleep(1);
        }
      }
      __syncthreads();
      asm volatile("" ::: "memory");

      const unsigned short* a0 = h0seq + (size_t)t * BH + frag_off;
      const unsigned short* a1 = a0 + 128;
      f32x4 acc00 = {}, acc01 = {}, acc10 = {}, acc11 = {};
#pragma unroll
      for (int ks = 0; ks < 8; ++ks) {
        s16x8 av0 = *(const s16x8*)(a0 + ks * 1024);
        s16x8 av1 = *(const s16x8*)(a1 + ks * 1024);
        acc00 = MFMA16(av0, wreg[ks][0], acc00);
        acc01 = MFMA16(av0, wreg[ks][1], acc01);
        acc10 = MFMA16(av1, wreg[ks][0], acc10);
        acc11 = MFMA16(av1, wreg[ks][1], acc11);
      }
#pragma unroll
      for (int r = 0; r < 4; ++r) {
        parts[wave][0][0][kq * 4 + r][colIdx] = acc00[r];
        parts[wave][0][1][kq * 4 + r][colIdx] = acc01[r];
        parts[wave][1][0][kq * 4 + r][colIdx] = acc10[r];
        parts[wave][1][1][kq * 4 + r][colIdx] = acc11[r];
      }
      __syncthreads();
      float g[4];
#pragma unroll
      for (int gi = 0; gi < 4; ++gi) {
        float s = gpre[gi];
        const int fi = gi >> 1, c = (gi & 1) * 8 + cjj;
#pragma unroll
        for (int w4 = 0; w4 < 4; ++w4) s += parts[w4][cb >> 4][fi][cb & 15][c];
        g[gi] = s;
      }
      const float i_ = sigf(g[0]), f_ = sigf(g[1]), gg = tanhf(g[2]), o_ = sigf(g[3]);
      creg = f_ * creg + i_ * gg;
      *(volatile unsigned short*)&h0seq[(size_t)(t + 1) * BH + blk * 256 + tid] =
          f2bf(o_ * tanhf(creg));

      asm volatile("s_waitcnt vmcnt(0)" ::: "memory");
      __syncthreads();
      if (tid == 0) *(volatile unsigned int*)&flags0[blk * 32] = (unsigned)(t + 1);
    }
  } else {
    // =================== L1 chain ===================
    for (int t = 1; t < TT; ++t) {
      if (wave == 0) {
        const unsigned t0 = (unsigned)t, t1 = (unsigned)(t - 1);
        for (;;) {
          unsigned a0 = ldflag(&flags0[(lane * 2 + 0) * 32]);
          unsigned b0 = ldflag(&flags0[(lane * 2 + 1) * 32]);
          unsigned a1 = ldflag(&flags1[(lane * 2 + 0) * 32]);
          unsigned b1 = ldflag(&flags1[(lane * 2 + 1) * 32]);
          bool ok = (min(a0, b0) >= t0) && (min(a1, b1) >= t1);
          if (__all(ok)) break;
          __builtin_amdgcn_s_sleep(1);
        }
      }
      __syncthreads();
      asm volatile("" ::: "memory");

      const unsigned short* base = (wave < 2)
                                       ? (h0seq + (size_t)t * BH)         // h0(t-1)
                                       : (hseq1 + (size_t)(t - 1) * BH);  // h1(t-2)
      const unsigned short* a0 = base + frag_off;
      const unsigned short* a1 = a0 + 128;
      f32x4 acc00 = {}, acc01 = {}, acc10 = {}, acc11 = {};
#pragma unroll
      for (int ks = 0; ks < 16; ++ks) {
        s16x8 av0 = *(const s16x8*)(a0 + ks * 1024);
        s16x8 av1 = *(const s16x8*)(a1 + ks * 1024);
        acc00 = MFMA16(av0, wreg[ks][0], acc00);
        acc01 = MFMA16(av0, wreg[ks][1], acc01);
        acc10 = MFMA16(av1, wreg[ks][0], acc10);
        acc11 = MFMA16(av1, wreg[ks][1], acc11);
      }
#pragma unroll
      for (int r = 0; r < 4; ++r) {
        parts[wave][0][0][kq * 4 + r][colIdx] = acc00[r];
        parts[wave][0][1][kq * 4 + r][colIdx] = acc01[r];
        parts[wave][1][0][kq * 4 + r][colIdx] = acc10[r];
        parts[wave][1][1][kq * 4 + r][colIdx] = acc11[r];
      }
      __syncthreads();
      float g[4];
#pragma unroll
      for (int gi = 0; gi < 4; ++gi) {
        float s = bsum[gi];
        const int fi = gi >> 1, c = (gi & 1) * 8 + cjj;
#pragma unroll
        for (int w4 = 0; w4 < 4; ++w4) s += parts[w4][cb >> 4][fi][cb & 15][c];
        g[gi] = s;
      }
      const float i_ = sigf(g[0]), f_ = sigf(g[1]), gg = tanhf(g[2]), o_ = sigf(g[3]);
      creg = f_ * creg + i_ * gg;
      const unsigned short hv = f2bf(o_ * tanhf(creg));
      *(volatile unsigned short*)&hseq1[(size_t)t * BH + blk * 256 + tid] = hv;
      hs_all[(size_t)t * BH + (size_t)cb * HH + jb + cjj] = hv;  // plain (GEMM copy)

      asm volatile("s_waitcnt vmcnt(0)" ::: "memory");
      __syncthreads();
      if (tid == 0) *(volatile unsigned int*)&flags1[blk * 32] = (unsigned)t;
    }
  }
}

// ---------------- host ----------------

extern "C" void kernel_launch(void* const* d_in, const int* in_sizes, int n_in,
                              void* d_out, int out_size, void* d_ws, size_t ws_size,
                              hipStream_t stream) {
  const int* captions = (const int*)d_in[1];
  const float* etab = (const float*)d_in[2];
  const float* pos = (const float*)d_in[3];
  const float* Wih0 = (const float*)d_in[4];
  const float* Whh0 = (const float*)d_in[5];
  const float* bih0 = (const float*)d_in[6];
  const float* bhh0 = (const float*)d_in[7];
  const float* Wih1 = (const float*)d_in[8];
  const float* Whh1 = (const float*)d_in[9];
  const float* bih1 = (const float*)d_in[10];
  const float* bhh1 = (const float*)d_in[11];
  const float* Wout = (const float*)d_in[12];
  const float* bout = (const float*)d_in[13];
  float* out = (float*)d_out;

  char* w = (char*)d_ws;
  auto alloc = [&](size_t bytes) {
    char* p = w;
    w += (bytes + 255) & ~(size_t)255;
    return p;
  };
  // layout: flags0(16KB) flags1(16KB) h0seq hseq1 hs_all ...
  unsigned int* flags0 = (unsigned int*)alloc(128 * 128);
  unsigned int* flags1 = (unsigned int*)alloc(128 * 128);
  unsigned short* h0seq = (unsigned short*)alloc((size_t)TT * BH * 2);   // block-major
  unsigned short* hseq1 = (unsigned short*)alloc((size_t)TT * BH * 2);   // block-major
  unsigned short* hs_all = (unsigned short*)alloc((size_t)4160 * HH * 2);// row-major

  unsigned short* Xb = (unsigned short*)alloc((size_t)MPAD * EE * 2);
  unsigned short* Wih0b = (unsigned short*)alloc((size_t)FH * EE * 2);
  unsigned short* Woutb = (unsigned short*)alloc((size_t)VV * HH * 2);
  float* G0pre = (float*)alloc((size_t)MROWS * FH * 4);

  // 1) zero read-before-write state: [flags0|flags1|h0seq slot0] and hseq1 slot0
  hipLaunchKernelGGL(zero2_k, dim3(40), dim3(256), 0, stream,
                     (uint4*)flags0, (int)((128 * 128 * 2 + BH * 2) / 16),
                     (uint4*)hseq1, (int)((BH * 2) / 16));
  // 2) convert Wih0 + Wout to bf16 (one kernel)
  hipLaunchKernelGGL(cvt2_k, dim3(4096), dim3(256), 0, stream,
                     (const float4*)Wih0, (u16x4*)Wih0b, FH * EE / 4,
                     (const float4*)Wout, (u16x4*)Woutb, VV * HH / 4);
  // 3) embeddings + pos -> X
  hipLaunchKernelGGL(embed_k, dim3(MPAD), dim3(256), 0, stream, captions, etab, pos, Xb);
  // 4) G0pre = X @ Wih0^T + bih0 + bhh0
  hipLaunchKernelGGL(gemm_bt, dim3(32, 32), dim3(256), 0, stream, Xb, Wih0b, EE, FH, bih0,
                     bhh0, G0pre);
  // 5) persistent recurrence, flat direct-poll barriers
  hipLaunchKernelGGL(lstm_persist, dim3(NBLK), dim3(256), 0, stream, Whh0, Wih1, Whh1, G0pre,
                     bih1, bhh1, h0seq, hseq1, hs_all, flags0, flags1);
  // 6) projection, j-major ordering
  hipLaunchKernelGGL(proj_gemm, dim3(8000), dim3(256), 0, stream, hs_all + (size_t)BH, Woutb,
                     bout, out);
  // 7) out[:, 0, :] = 0
  hipLaunchKernelGGL(zero_out_t0, dim3(125, 32), dim3(256), 0, stream, out);
}

// Round 12
// 1353.912 us; speedup vs baseline: 1.3389x; 1.0093x over previous
//
#include <hip/hip_runtime.h>
#include <hip/hip_bf16.h>
#include <math.h>

typedef __attribute__((ext_vector_type(4))) float f32x4;
typedef __attribute__((ext_vector_type(8))) short s16x8;
typedef __attribute__((ext_vector_type(4))) unsigned short u16x4;

#define MFMA16(a, b, c) __builtin_amdgcn_mfma_f32_16x16x32_bf16(a, b, c, 0, 0, 0)

static constexpr int BB = 32, TT = 128, EE = 512, HH = 1024, VV = 32000;
static constexpr int FH = 4 * HH;           // 4096 gate rows
static constexpr int MROWS = (TT - 1) * BB; // 4064 valid rows
static constexpr int MPAD = 4096;
static constexpr int BH = BB * HH;          // 32768
static constexpr int NBLK = 256;            // recurrence grid

__device__ __forceinline__ unsigned short f2bf(float f) {
  unsigned int u = __float_as_uint(f);
  u = (u + 0x7FFFu + ((u >> 16) & 1u)) >> 16;
  return (unsigned short)u;
}
__device__ __forceinline__ float sigf(float x) { return 1.f / (1.f + __expf(-x)); }

__device__ __forceinline__ s16x8 pack8f(const float* p) {
  float4 x = *(const float4*)p;
  float4 y = *(const float4*)(p + 4);
  s16x8 r;
  r[0] = (short)f2bf(x.x); r[1] = (short)f2bf(x.y);
  r[2] = (short)f2bf(x.z); r[3] = (short)f2bf(x.w);
  r[4] = (short)f2bf(y.x); r[5] = (short)f2bf(y.y);
  r[6] = (short)f2bf(y.z); r[7] = (short)f2bf(y.w);
  return r;
}

__device__ __forceinline__ void gl_lds16(const void* g, void* l) {
  __builtin_amdgcn_global_load_lds(
      (const __attribute__((address_space(1))) unsigned int*)g,
      (__attribute__((address_space(3))) unsigned int*)l, 16, 0, 0);
}

__device__ __forceinline__ unsigned ldflag(const unsigned int* p) {
  return __hip_atomic_load(p, __ATOMIC_RELAXED, __HIP_MEMORY_SCOPE_AGENT);
}

// ---------------- zero / convert / embed ----------------

__global__ void zero2_k(uint4* __restrict__ p0, int n0, uint4* __restrict__ p1, int n1) {
  int i = blockIdx.x * blockDim.x + threadIdx.x;
  int stride = gridDim.x * blockDim.x;
  uint4 z = {0u, 0u, 0u, 0u};
  for (int k = i; k < n0; k += stride) p0[k] = z;
  for (int k = i; k < n1; k += stride) p1[k] = z;
}

__global__ void cvt2_k(const float4* __restrict__ a, u16x4* __restrict__ ao, int na4,
                       const float4* __restrict__ b, u16x4* __restrict__ bo, int nb4) {
  int i = blockIdx.x * blockDim.x + threadIdx.x;
  int stride = gridDim.x * blockDim.x;
  for (int k = i; k < na4; k += stride) {
    float4 v = a[k];
    u16x4 o;
    o[0] = f2bf(v.x); o[1] = f2bf(v.y); o[2] = f2bf(v.z); o[3] = f2bf(v.w);
    ao[k] = o;
  }
  for (int k = i; k < nb4; k += stride) {
    float4 v = b[k];
    u16x4 o;
    o[0] = f2bf(v.x); o[1] = f2bf(v.y); o[2] = f2bf(v.z); o[3] = f2bf(v.w);
    bo[k] = o;
  }
}

__global__ __launch_bounds__(256) void embed_k(const int* __restrict__ captions,
                                               const float* __restrict__ etab,
                                               const float* __restrict__ pos,
                                               unsigned short* __restrict__ X) {
  const int m = blockIdx.x;  // row = t*32 + b
  const int t = m >> 5, b = m & 31;
  if (t < TT - 1) {
    const int tok = captions[b * TT + t];
    const float* er = etab + (size_t)tok * EE;
    for (int e = threadIdx.x; e < EE; e += 256)
      X[(size_t)m * EE + e] = f2bf(er[e] + pos[e]);
  } else {
    for (int e = threadIdx.x; e < EE; e += 256) X[(size_t)m * EE + e] = 0;
  }
}

__global__ void zero_out_t0(float* __restrict__ out) {
  out[(size_t)blockIdx.y * TT * VV + blockIdx.x * 256 + threadIdx.x] = 0.f;
}

// ---------------- G0pre GEMM (C = A @ B^T + b0 + b1), m97 staging ----------

__global__ __launch_bounds__(256) void gemm_bt(const unsigned short* __restrict__ A,
                                               const unsigned short* __restrict__ Bm,
                                               int K, int N,
                                               const float* __restrict__ bias0,
                                               const float* __restrict__ bias1,
                                               float* __restrict__ Cout) {
  __shared__ unsigned short As[128 * 64];
  __shared__ unsigned short Bs[128 * 64];
  const int tid = threadIdx.x;
  const int lane = tid & 63, wave = tid >> 6;
  const int wm = wave & 1, wn = wave >> 1;
  const int m0 = blockIdx.x * 128, n0 = blockIdx.y * 128;
  const int sch = (lane & 7) * 8;
  const int srbase = wave * 32 + (lane >> 3);
  f32x4 acc[4][4] = {};

  for (int k0 = 0; k0 < K; k0 += 64) {
    __syncthreads();
#pragma unroll
    for (int i = 0; i < 4; ++i) {
      const int r = srbase + i * 8;
      gl_lds16(&A[(size_t)(m0 + r) * K + k0 + sch], &As[(wave * 4 + i) * 512]);
      gl_lds16(&Bm[(size_t)(n0 + r) * K + k0 + sch], &Bs[(wave * 4 + i) * 512]);
    }
    __syncthreads();
#pragma unroll
    for (int kk = 0; kk < 64; kk += 32) {
      s16x8 af[4], bf[4];
#pragma unroll
      for (int f = 0; f < 4; ++f) {
        af[f] = *(const s16x8*)(&As[(wm * 64 + f * 16 + (lane & 15)) * 64 + kk + (lane >> 4) * 8]);
        bf[f] = *(const s16x8*)(&Bs[(wn * 64 + f * 16 + (lane & 15)) * 64 + kk + (lane >> 4) * 8]);
      }
#pragma unroll
      for (int mi = 0; mi < 4; ++mi)
#pragma unroll
        for (int ni = 0; ni < 4; ++ni)
          acc[mi][ni] = MFMA16(af[mi], bf[ni], acc[mi][ni]);
    }
  }

#pragma unroll
  for (int mi = 0; mi < 4; ++mi) {
#pragma unroll
    for (int ni = 0; ni < 4; ++ni) {
      const int col = n0 + wn * 64 + ni * 16 + (lane & 15);
      float bs = bias0[col] + bias1[col];
      const int mbase = m0 + wm * 64 + mi * 16 + (lane >> 4) * 4;
#pragma unroll
      for (int r = 0; r < 4; ++r) {
        int m = mbase + r;
        if (m < MROWS) Cout[(size_t)m * N + col] = acc[mi][ni][r] + bs;
      }
    }
  }
}

// ---------------- projection GEMM, 256x256 tile (halves staging traffic) ---
// 512 threads, 8 waves (2x4). Per wave: 128x64 output, acc[8][4]. BK=64.
// Grid 2000 = 16 m-tiles x 125 n-tiles, j-major (T = j*125+n): concurrent
// window spans ~2 j-stripes -> A L2-resident, Wout IC-resident.

__global__ __launch_bounds__(512, 1) void proj_gemm(const unsigned short* __restrict__ hsA,
                                                    const unsigned short* __restrict__ Woutb,
                                                    const float* __restrict__ bout,
                                                    float* __restrict__ out) {
  __shared__ unsigned short As[256 * 64];  // 32KB
  __shared__ unsigned short Bs[256 * 64];  // 32KB
  const int tid = threadIdx.x;
  const int lane = tid & 63, wave = tid >> 6;    // 8 waves
  const int wm = wave & 1, wn = wave >> 1;       // wm 0..1, wn 0..3
  const int T = blockIdx.x;
  const int j = T / 125, n = T % 125;
  const int m0 = j * 256, n0 = n * 256;
  const int sch = (lane & 7) * 8;                // k element offset
  const int rbase = tid >> 3;                    // staging row (this thread)
  f32x4 acc[8][4] = {};

  for (int k0 = 0; k0 < HH; k0 += 64) {
    __syncthreads();
#pragma unroll
    for (int i = 0; i < 4; ++i) {
      const int r = rbase + i * 64;  // rows 0..255 over 4 issues
      // LDS dest: wave-uniform base; HW adds lane*16B
      gl_lds16(&hsA[(size_t)(m0 + r) * HH + k0 + sch], &As[(wave * 64 + i * 512) * 8]);
      gl_lds16(&Woutb[(size_t)(n0 + r) * HH + k0 + sch], &Bs[(wave * 64 + i * 512) * 8]);
    }
    __syncthreads();
#pragma unroll
    for (int kk = 0; kk < 64; kk += 32) {
      s16x8 af[8], bf[4];
#pragma unroll
      for (int f = 0; f < 8; ++f)
        af[f] = *(const s16x8*)(&As[(wm * 128 + f * 16 + (lane & 15)) * 64 + kk + (lane >> 4) * 8]);
#pragma unroll
      for (int f = 0; f < 4; ++f)
        bf[f] = *(const s16x8*)(&Bs[(wn * 64 + f * 16 + (lane & 15)) * 64 + kk + (lane >> 4) * 8]);
#pragma unroll
      for (int mi = 0; mi < 8; ++mi)
#pragma unroll
        for (int ni = 0; ni < 4; ++ni)
          acc[mi][ni] = MFMA16(af[mi], bf[ni], acc[mi][ni]);
    }
  }

#pragma unroll
  for (int mi = 0; mi < 8; ++mi) {
#pragma unroll
    for (int ni = 0; ni < 4; ++ni) {
      const int col = n0 + wn * 64 + ni * 16 + (lane & 15);
      const float bs = bout[col];
      const int mbase = m0 + wm * 128 + mi * 16 + (lane >> 4) * 4;
#pragma unroll
      for (int r2 = 0; r2 < 4; ++r2) {
        const int m = mbase + r2;
        if (m < MROWS) {
          const int tt = m >> 5, b2 = m & 31;
          out[((size_t)b2 * TT + tt + 1) * VV + col] = acc[mi][ni][r2] + bs;
        }
      }
    }
  }
}

// ---------------- persistent 2-layer LSTM, flat direct-poll barriers ------

__global__ __launch_bounds__(256, 1) void lstm_persist(
    const float* __restrict__ Whh0f, const float* __restrict__ Wih1f,
    const float* __restrict__ Whh1f, const float* __restrict__ G0pre,
    const float* __restrict__ bih1, const float* __restrict__ bhh1,
    unsigned short* __restrict__ h0seq, unsigned short* __restrict__ hseq1,
    unsigned short* __restrict__ hs_all,
    unsigned int* __restrict__ flags0, unsigned int* __restrict__ flags1) {
  __shared__ float parts[4][2][2][16][16];  // 8KB
  const int bid = blockIdx.x;
  const int layer = bid >> 7;
  const int blk = bid & 127;
  const int tid = threadIdx.x, lane = tid & 63, wave = tid >> 6;
  const int jb = blk * 8;
  const int colIdx = lane & 15;
  const int kq = lane >> 4;
  const int wrow0 = (colIdx >> 3) * HH + jb + (colIdx & 7);

  const int cb = tid >> 3, cjj = tid & 7;
  float creg = 0.f;
  float bsum[4];
  if (layer == 1) {
#pragma unroll
    for (int gi = 0; gi < 4; ++gi)
      bsum[gi] = bih1[gi * HH + jb + cjj] + bhh1[gi * HH + jb + cjj];
  }

  // ---- recurrent weights into registers (fp32 -> bf16) ----
  s16x8 wreg[16][2];
  const int kb = (layer == 0) ? wave * 256 : (wave & 1) * 512;
  if (layer == 0) {
#pragma unroll
    for (int fi = 0; fi < 2; ++fi) {
      const float* wp = Whh0f + (size_t)(wrow0 + fi * 2 * HH) * HH + kb + kq * 8;
#pragma unroll
      for (int ks = 0; ks < 8; ++ks) wreg[ks][fi] = pack8f(wp + ks * 32);
    }
  } else {
    const float* Wsrc = (wave < 2) ? Wih1f : Whh1f;
#pragma unroll
    for (int fi = 0; fi < 2; ++fi) {
      const float* wp = Wsrc + (size_t)(wrow0 + fi * 2 * HH) * HH + kb + kq * 8;
#pragma unroll
      for (int ks = 0; ks < 16; ++ks) wreg[ks][fi] = pack8f(wp + ks * 32);
    }
  }

  const int frag_off = (kb >> 3) * 256 + kq * 256 + (lane & 15) * 8;

  if (layer == 0) {
    // =================== L0 chain ===================
    for (int t = 0; t < TT - 1; ++t) {
      float gpre[4];
#pragma unroll
      for (int gi = 0; gi < 4; ++gi)
        gpre[gi] = G0pre[((size_t)t * BB + cb) * FH + gi * HH + jb + cjj];

      if (t > 0 && wave == 0) {
        const unsigned tgt = (unsigned)t;
        for (;;) {
          unsigned a = ldflag(&flags0[(lane * 2 + 0) * 32]);
          unsigned b = ldflag(&flags0[(lane * 2 + 1) * 32]);
          if (__all(min(a, b) >= tgt)) break;
          __builtin_amdgcn_s_sleep(1);
        }
      }
      __syncthreads();
      asm volatile("" ::: "memory");

      const unsigned short* a0 = h0seq + (size_t)t * BH + frag_off;
      const unsigned short* a1 = a0 + 128;
      f32x4 acc00 = {}, acc01 = {}, acc10 = {}, acc11 = {};
#pragma unroll
      for (int ks = 0; ks < 8; ++ks) {
        s16x8 av0 = *(const s16x8*)(a0 + ks * 1024);
        s16x8 av1 = *(const s16x8*)(a1 + ks * 1024);
        acc00 = MFMA16(av0, wreg[ks][0], acc00);
        acc01 = MFMA16(av0, wreg[ks][1], acc01);
        acc10 = MFMA16(av1, wreg[ks][0], acc10);
        acc11 = MFMA16(av1, wreg[ks][1], acc11);
      }
#pragma unroll
      for (int r = 0; r < 4; ++r) {
        parts[wave][0][0][kq * 4 + r][colIdx] = acc00[r];
        parts[wave][0][1][kq * 4 + r][colIdx] = acc01[r];
        parts[wave][1][0][kq * 4 + r][colIdx] = acc10[r];
        parts[wave][1][1][kq * 4 + r][colIdx] = acc11[r];
      }
      __syncthreads();
      float g[4];
#pragma unroll
      for (int gi = 0; gi < 4; ++gi) {
        float s = gpre[gi];
        const int fi = gi >> 1, c = (gi & 1) * 8 + cjj;
#pragma unroll
        for (int w4 = 0; w4 < 4; ++w4) s += parts[w4][cb >> 4][fi][cb & 15][c];
        g[gi] = s;
      }
      const float i_ = sigf(g[0]), f_ = sigf(g[1]), gg = tanhf(g[2]), o_ = sigf(g[3]);
      creg = f_ * creg + i_ * gg;
      *(volatile unsigned short*)&h0seq[(size_t)(t + 1) * BH + blk * 256 + tid] =
          f2bf(o_ * tanhf(creg));

      asm volatile("s_waitcnt vmcnt(0)" ::: "memory");
      __syncthreads();
      if (tid == 0) *(volatile unsigned int*)&flags0[blk * 32] = (unsigned)(t + 1);
    }
  } else {
    // =================== L1 chain ===================
    for (int t = 1; t < TT; ++t) {
      if (wave == 0) {
        const unsigned t0 = (unsigned)t, t1 = (unsigned)(t - 1);
        for (;;) {
          unsigned a0 = ldflag(&flags0[(lane * 2 + 0) * 32]);
          unsigned b0 = ldflag(&flags0[(lane * 2 + 1) * 32]);
          unsigned a1 = ldflag(&flags1[(lane * 2 + 0) * 32]);
          unsigned b1 = ldflag(&flags1[(lane * 2 + 1) * 32]);
          bool ok = (min(a0, b0) >= t0) && (min(a1, b1) >= t1);
          if (__all(ok)) break;
          __builtin_amdgcn_s_sleep(1);
        }
      }
      __syncthreads();
      asm volatile("" ::: "memory");

      const unsigned short* base = (wave < 2)
                                       ? (h0seq + (size_t)t * BH)         // h0(t-1)
                                       : (hseq1 + (size_t)(t - 1) * BH);  // h1(t-2)
      const unsigned short* a0 = base + frag_off;
      const unsigned short* a1 = a0 + 128;
      f32x4 acc00 = {}, acc01 = {}, acc10 = {}, acc11 = {};
#pragma unroll
      for (int ks = 0; ks < 16; ++ks) {
        s16x8 av0 = *(const s16x8*)(a0 + ks * 1024);
        s16x8 av1 = *(const s16x8*)(a1 + ks * 1024);
        acc00 = MFMA16(av0, wreg[ks][0], acc00);
        acc01 = MFMA16(av0, wreg[ks][1], acc01);
        acc10 = MFMA16(av1, wreg[ks][0], acc10);
        acc11 = MFMA16(av1, wreg[ks][1], acc11);
      }
#pragma unroll
      for (int r = 0; r < 4; ++r) {
        parts[wave][0][0][kq * 4 + r][colIdx] = acc00[r];
        parts[wave][0][1][kq * 4 + r][colIdx] = acc01[r];
        parts[wave][1][0][kq * 4 + r][colIdx] = acc10[r];
        parts[wave][1][1][kq * 4 + r][colIdx] = acc11[r];
      }
      __syncthreads();
      float g[4];
#pragma unroll
      for (int gi = 0; gi < 4; ++gi) {
        float s = bsum[gi];
        const int fi = gi >> 1, c = (gi & 1) * 8 + cjj;
#pragma unroll
        for (int w4 = 0; w4 < 4; ++w4) s += parts[w4][cb >> 4][fi][cb & 15][c];
        g[gi] = s;
      }
      const float i_ = sigf(g[0]), f_ = sigf(g[1]), gg = tanhf(g[2]), o_ = sigf(g[3]);
      creg = f_ * creg + i_ * gg;
      const unsigned short hv = f2bf(o_ * tanhf(creg));
      *(volatile unsigned short*)&hseq1[(size_t)t * BH + blk * 256 + tid] = hv;
      hs_all[(size_t)t * BH + (size_t)cb * HH + jb + cjj] = hv;  // plain (GEMM copy)

      asm volatile("s_waitcnt vmcnt(0)" ::: "memory");
      __syncthreads();
      if (tid == 0) *(volatile unsigned int*)&flags1[blk * 32] = (unsigned)t;
    }
  }
}

// ---------------- host ----------------

extern "C" void kernel_launch(void* const* d_in, const int* in_sizes, int n_in,
                              void* d_out, int out_size, void* d_ws, size_t ws_size,
                              hipStream_t stream) {
  const int* captions = (const int*)d_in[1];
  const float* etab = (const float*)d_in[2];
  const float* pos = (const float*)d_in[3];
  const float* Wih0 = (const float*)d_in[4];
  const float* Whh0 = (const float*)d_in[5];
  const float* bih0 = (const float*)d_in[6];
  const float* bhh0 = (const float*)d_in[7];
  const float* Wih1 = (const float*)d_in[8];
  const float* Whh1 = (const float*)d_in[9];
  const float* bih1 = (const float*)d_in[10];
  const float* bhh1 = (const float*)d_in[11];
  const float* Wout = (const float*)d_in[12];
  const float* bout = (const float*)d_in[13];
  float* out = (float*)d_out;

  char* w = (char*)d_ws;
  auto alloc = [&](size_t bytes) {
    char* p = w;
    w += (bytes + 255) & ~(size_t)255;
    return p;
  };
  // layout: flags0(16KB) flags1(16KB) h0seq hseq1 hs_all ...
  unsigned int* flags0 = (unsigned int*)alloc(128 * 128);
  unsigned int* flags1 = (unsigned int*)alloc(128 * 128);
  unsigned short* h0seq = (unsigned short*)alloc((size_t)TT * BH * 2);   // block-major
  unsigned short* hseq1 = (unsigned short*)alloc((size_t)TT * BH * 2);   // block-major
  unsigned short* hs_all = (unsigned short*)alloc((size_t)4160 * HH * 2);// row-major

  unsigned short* Xb = (unsigned short*)alloc((size_t)MPAD * EE * 2);
  unsigned short* Wih0b = (unsigned short*)alloc((size_t)FH * EE * 2);
  unsigned short* Woutb = (unsigned short*)alloc((size_t)VV * HH * 2);
  float* G0pre = (float*)alloc((size_t)MROWS * FH * 4);

  // 1) zero read-before-write state: [flags0|flags1|h0seq slot0] and hseq1 slot0
  hipLaunchKernelGGL(zero2_k, dim3(40), dim3(256), 0, stream,
                     (uint4*)flags0, (int)((128 * 128 * 2 + BH * 2) / 16),
                     (uint4*)hseq1, (int)((BH * 2) / 16));
  // 2) convert Wih0 + Wout to bf16 (one kernel)
  hipLaunchKernelGGL(cvt2_k, dim3(4096), dim3(256), 0, stream,
                     (const float4*)Wih0, (u16x4*)Wih0b, FH * EE / 4,
                     (const float4*)Wout, (u16x4*)Woutb, VV * HH / 4);
  // 3) embeddings + pos -> X
  hipLaunchKernelGGL(embed_k, dim3(MPAD), dim3(256), 0, stream, captions, etab, pos, Xb);
  // 4) G0pre = X @ Wih0^T + bih0 + bhh0
  hipLaunchKernelGGL(gemm_bt, dim3(32, 32), dim3(256), 0, stream, Xb, Wih0b, EE, FH, bih0,
                     bhh0, G0pre);
  // 5) persistent recurrence, flat direct-poll barriers
  hipLaunchKernelGGL(lstm_persist, dim3(NBLK), dim3(256), 0, stream, Whh0, Wih1, Whh1, G0pre,
                     bih1, bhh1, h0seq, hseq1, hs_all, flags0, flags1);
  // 6) projection, 256x256 tile, j-major
  hipLaunchKernelGGL(proj_gemm, dim3(16 * 125), dim3(512), 0, stream, hs_all + (size_t)BH,
                     Woutb, bout, out);
  // 7) out[:, 0, :] = 0
  hipLaunchKernelGGL(zero_out_t0, dim3(125, 32), dim3(256), 0, stream, out);
}